// Round 7
// baseline (140.700 us; speedup 1.0000x reference)
//
#include <hip/hip_runtime.h>
#include <hip/hip_cooperative_groups.h>

namespace cg = cooperative_groups;

#define S_LEN  64000
#define B_N    64
#define TPB    512
#define WPB    8                // waves per block
#define MCH    32               // steps per wave (serial chain, ILP-2 inside)
#define BSTEPS (WPB * MCH)      // 256 steps per block
#define NBLK   (S_LEN / BSTEPS) // 250 blocks -> 1/CU, coop-launch safe
#define SC_T   256              // scan threads (covers 250 macros, 1 each)

struct Aff { float m00, m01, m10, m11, v0, v1; };

__device__ __forceinline__ Aff aff_id() {
    Aff r; r.m00 = 1.f; r.m01 = 0.f; r.m10 = 0.f; r.m11 = 1.f; r.v0 = 0.f; r.v1 = 0.f;
    return r;
}

// X ∘ Y : apply Y first, then X
__device__ __forceinline__ Aff aff_comp(const Aff& X, const Aff& Y) {
    Aff r;
    r.m00 = fmaf(X.m00, Y.m00, X.m01 * Y.m10);
    r.m01 = fmaf(X.m00, Y.m01, X.m01 * Y.m11);
    r.m10 = fmaf(X.m10, Y.m00, X.m11 * Y.m10);
    r.m11 = fmaf(X.m10, Y.m01, X.m11 * Y.m11);
    r.v0  = fmaf(X.m00, Y.v0, fmaf(X.m01, Y.v1, X.v0));
    r.v1  = fmaf(X.m10, Y.v0, fmaf(X.m11, Y.v1, X.v1));
    return r;
}

// Per-step transform: state' = A*state + c, A = 2H - I, c = 2*gHBx
__device__ __forceinline__ Aff svf_step(float g, float R, float x) {
    Aff a;
    float T  = 1.0f / fmaf(g, g + R, 1.0f);
    float gT = g * T;
    a.m00 = fmaf(2.0f, T, -1.0f);
    a.m01 = -2.0f * gT;
    a.m10 =  2.0f * gT;
    a.m11 = fmaf(2.0f, fmaf(R, gT, T), -1.0f);
    a.v0  = a.m10 * x;
    a.v1  = g * a.v0;
    return a;
}

// LDS staging: stride 7 floats -> lanes hit each bank 2x max (free)
__device__ __forceinline__ void aff_store_lds(float* p, const Aff& a) {
    p[0] = a.m00; p[1] = a.m01; p[2] = a.m10; p[3] = a.m11; p[4] = a.v0; p[5] = a.v1;
}
__device__ __forceinline__ Aff aff_load_lds(const float* p) {
    Aff a; a.m00 = p[0]; a.m01 = p[1]; a.m10 = p[2]; a.m11 = p[3]; a.v0 = p[4]; a.v1 = p[5];
    return a;
}
// Packed global Aff: 3 x float2
__device__ __forceinline__ void aff_store_g(float2* p, const Aff& a) {
    p[0] = make_float2(a.m00, a.m01);
    p[1] = make_float2(a.m10, a.m11);
    p[2] = make_float2(a.v0,  a.v1);
}
__device__ __forceinline__ Aff aff_load_g(const float2* p) {
    float2 x = p[0], y = p[1], z = p[2];
    Aff a; a.m00 = x.x; a.m01 = x.y; a.m10 = y.x; a.m11 = y.y; a.v0 = z.x; a.v1 = z.y;
    return a;
}

// wsMac layout: [batch][block] -> phase-2 scan reads contiguous per batch.
__global__ __launch_bounds__(TPB, 2) void k_fused(
    const float* __restrict__ audio, const float* __restrict__ g,
    const float* __restrict__ twoR, const float* __restrict__ mix,
    float2* __restrict__ wsMac, float2* __restrict__ sEntry,
    float* __restrict__ out)
{
    __shared__ float affs[WPB * B_N * 7];   // 14.3 KB: per-wave micro Affs
    __shared__ float tile[128 * 65];        // 33.3 KB: output transpose tile
    __shared__ Aff wt[SC_T / 64];           // phase-2 cross-wave totals

    const int b   = threadIdx.x & 63;       // lane = batch
    const int w   = threadIdx.x >> 6;       // wave id 0..7
    const int blk = blockIdx.x;
    const int base = (blk * BSTEPS + w * MCH) * B_N + b;

    // ---- Phase 1: micro transform (32 steps, ILP-2); hold g,R only ----
    float gv[MCH], Rv[MCH];
    Aff lo = aff_id(), hi = aff_id();
#pragma unroll
    for (int i = 0; i < MCH / 2; ++i) {
        const int i0 = base + i * B_N;
        const int i1 = base + (i + MCH / 2) * B_N;
        gv[i] = g[i0]; Rv[i] = twoR[i0]; float x0 = audio[i0];
        gv[i + MCH / 2] = g[i1]; Rv[i + MCH / 2] = twoR[i1]; float x1 = audio[i1];
        lo = aff_comp(svf_step(gv[i],           Rv[i],           x0), lo);
        hi = aff_comp(svf_step(gv[i + MCH / 2], Rv[i + MCH / 2], x1), hi);
    }
    Aff micro = aff_comp(hi, lo);
    aff_store_lds(&affs[(w * B_N + b) * 7], micro);
    __syncthreads();

    if (w == 0) {                           // block macro = 8 micros composed
        Aff M = micro;
#pragma unroll
        for (int j = 1; j < WPB; ++j)
            M = aff_comp(aff_load_lds(&affs[(j * B_N + b) * 7]), M);
        aff_store_g(&wsMac[((long)b * NBLK + blk) * 3], M);
    }

    cg::grid_group grid = cg::this_grid();
    grid.sync();

    // ---- Phase 2: blocks 0..63 scan the 250 macros of batch = blk ----
    if (blk < B_N) {
        const int t = threadIdx.x, lane = t & 63, wv = t >> 6;
        const bool act = (t < SC_T);
        Aff acc = aff_id();
        if (act) {
            if (t < NBLK) acc = aff_load_g(&wsMac[((long)blk * NBLK + t) * 3]);
#pragma unroll
            for (int d = 1; d < 64; d <<= 1) {
                Aff o;
                o.m00 = __shfl_up(acc.m00, (unsigned)d, 64);
                o.m01 = __shfl_up(acc.m01, (unsigned)d, 64);
                o.m10 = __shfl_up(acc.m10, (unsigned)d, 64);
                o.m11 = __shfl_up(acc.m11, (unsigned)d, 64);
                o.v0  = __shfl_up(acc.v0,  (unsigned)d, 64);
                o.v1  = __shfl_up(acc.v1,  (unsigned)d, 64);
                if (lane >= d) acc = aff_comp(acc, o);
            }
            if (lane == 63) wt[wv] = acc;
        }
        __syncthreads();
        if (act && t < NBLK) {
            // exclusive prefix within wave
            Aff E;
            E.m00 = __shfl_up(acc.m00, 1u, 64);
            E.m01 = __shfl_up(acc.m01, 1u, 64);
            E.m10 = __shfl_up(acc.m10, 1u, 64);
            E.m11 = __shfl_up(acc.m11, 1u, 64);
            E.v0  = __shfl_up(acc.v0,  1u, 64);
            E.v1  = __shfl_up(acc.v1,  1u, 64);
            if (lane == 0) E = aff_id();
            Aff P = aff_id();
            for (int j = 0; j < wv; ++j) P = aff_comp(wt[j], P);
            E = aff_comp(E, P);
            // entry state of macro t: E applied to s0 = (1,1)
            float e0 = E.m00 + E.m01 + E.v0;
            float e1 = E.m10 + E.m11 + E.v1;
            sEntry[t * B_N + blk] = make_float2(e0, e1);
        }
    }
    grid.sync();

    // ---- Phase 3: per-wave LDS prefix + 32-step replay ----
    float2 sm = sEntry[blk * B_N + b];      // coalesced
    Aff P = aff_id();
    for (int j = 0; j < w; ++j)
        P = aff_comp(aff_load_lds(&affs[(j * B_N + b) * 7]), P);
    float s0 = fmaf(P.m00, sm.x, fmaf(P.m01, sm.y, P.v0));
    float s1 = fmaf(P.m10, sm.x, fmaf(P.m11, sm.y, P.v1));

    // two rounds of 128 steps so the transpose tile stays at 33 KB
    for (int round = 0; round < 2; ++round) {
        if ((w >> 2) == round) {
            const int wl = w & 3;
#pragma unroll
            for (int i = 0; i < MCH; ++i) {
                const int idx = base + i * B_N;
                float x  = audio[idx];      // L3-warm re-read
                float m0 = mix[idx * 3], m1 = mix[idx * 3 + 1], m2 = mix[idx * 3 + 2];
                float gg = gv[i], R = Rv[i];
                float T  = 1.0f / fmaf(gg, gg + R, 1.0f);
                float gT = gg * T;
                float b0 = gT * x;
                float b1 = gg * b0;
                float Y0 = fmaf(T, s0, fmaf(-gT, s1, b0));
                float Y1 = fmaf(gT, s0, fmaf(fmaf(R, gT, T), s1, b1));
                s0 = fmaf(2.0f, Y0, -s0);
                s1 = fmaf(2.0f, Y1, -s1);
                float yh = x - fmaf(R, Y0, Y1);
                float y  = fmaf(R * m0, Y0, fmaf(m1, Y1, m2 * yh));
                tile[(wl * MCH + i) * 65 + b] = y;
            }
        }
        __syncthreads();
        // out[r][blk*256 + round*128 + col]: 64-lane contiguous 256 B stores;
        // LDS reads stride-65 -> 2 lanes/bank (free)
        const int col = threadIdx.x & 127;
        const int r0  = threadIdx.x >> 7;
        const int colbase = blk * BSTEPS + round * 128;
#pragma unroll
        for (int r = r0; r < B_N; r += 4)
            out[r * S_LEN + colbase + col] = tile[col * 65 + r];
        if (round == 0) __syncthreads();
    }
}

extern "C" void kernel_launch(void* const* d_in, const int* in_sizes, int n_in,
                              void* d_out, int out_size, void* d_ws, size_t ws_size,
                              hipStream_t stream)
{
    const float* audio = (const float*)d_in[0];
    const float* g     = (const float*)d_in[1];
    const float* twoR  = (const float*)d_in[2];
    const float* mix   = (const float*)d_in[3];
    float* out = (float*)d_out;

    float2* wsMac  = (float2*)d_ws;                 // 64*NBLK*3 float2 (384 KB)
    float2* sEntry = wsMac + (long)B_N * NBLK * 3;  // NBLK*64 float2 (128 KB)

    void* args[] = { (void*)&audio, (void*)&g, (void*)&twoR, (void*)&mix,
                     (void*)&wsMac, (void*)&sEntry, (void*)&out };
    hipLaunchCooperativeKernel((void*)k_fused, dim3(NBLK), dim3(TPB),
                               args, 0, stream);
}

// Round 8
// 37.970 us; speedup vs baseline: 3.7056x; 3.7056x over previous
//
#include <hip/hip_runtime.h>

#define S_LEN  64000
#define B_N    64
#define MCH    8            // steps per micro-chunk (one wave's serial chain)
#define WPB    8            // waves per block (micros per macro)
#define BSTEPS (MCH * WPB)  // 64 steps per block / macro
#define NBLK   (S_LEN / BSTEPS) // 1000 macro chunks
#define SC_T   1024         // scan threads: one macro per thread (>= NBLK)

struct Aff { float m00, m01, m10, m11, v0, v1; };

__device__ __forceinline__ Aff aff_id() {
    Aff r; r.m00 = 1.f; r.m01 = 0.f; r.m10 = 0.f; r.m11 = 1.f; r.v0 = 0.f; r.v1 = 0.f;
    return r;
}

// X ∘ Y : apply Y first, then X
__device__ __forceinline__ Aff aff_comp(const Aff& X, const Aff& Y) {
    Aff r;
    r.m00 = fmaf(X.m00, Y.m00, X.m01 * Y.m10);
    r.m01 = fmaf(X.m00, Y.m01, X.m01 * Y.m11);
    r.m10 = fmaf(X.m10, Y.m00, X.m11 * Y.m10);
    r.m11 = fmaf(X.m10, Y.m01, X.m11 * Y.m11);
    r.v0  = fmaf(X.m00, Y.v0, fmaf(X.m01, Y.v1, X.v0));
    r.v1  = fmaf(X.m10, Y.v0, fmaf(X.m11, Y.v1, X.v1));
    return r;
}

// Per-step transform: state' = A*state + c, A = 2H - I, c = 2*gHBx
__device__ __forceinline__ Aff svf_step(float g, float R, float x) {
    Aff a;
    float T  = 1.0f / fmaf(g, g + R, 1.0f);
    float gT = g * T;
    a.m00 = fmaf(2.0f, T, -1.0f);
    a.m01 = -2.0f * gT;
    a.m10 =  2.0f * gT;
    a.m11 = fmaf(2.0f, fmaf(R, gT, T), -1.0f);
    a.v0  = a.m10 * x;
    a.v1  = g * a.v0;
    return a;
}

// LDS staging, stride 7 floats per (micro, batch) -> 2 lanes/bank max (free)
__device__ __forceinline__ void aff_store_lds(float* p, const Aff& a) {
    p[0] = a.m00; p[1] = a.m01; p[2] = a.m10; p[3] = a.m11; p[4] = a.v0; p[5] = a.v1;
}
__device__ __forceinline__ Aff aff_load_lds(const float* p) {
    Aff a; a.m00 = p[0]; a.m01 = p[1]; a.m10 = p[2]; a.m11 = p[3]; a.v0 = p[4]; a.v1 = p[5];
    return a;
}
// Packed global Aff: 3 x float2 at element (p*64+b)*3 (8-B aligned)
__device__ __forceinline__ void aff_store_g(float2* p, const Aff& a) {
    p[0] = make_float2(a.m00, a.m01);
    p[1] = make_float2(a.m10, a.m11);
    p[2] = make_float2(a.v0,  a.v1);
}
__device__ __forceinline__ Aff aff_load_g(const float2* p) {
    float2 x = p[0], y = p[1], z = p[2];
    Aff a; a.m00 = x.x; a.m01 = x.y; a.m10 = y.x; a.m11 = y.y; a.v0 = z.x; a.v1 = z.y;
    return a;
}

// Pass 1: wave w composes 8-step micro transform; block composes its 8
// micros (64 steps) into one macro transform via LDS. Lane = batch.
__global__ __launch_bounds__(512, 4) void k_macro(
    const float* __restrict__ audio, const float* __restrict__ g,
    const float* __restrict__ twoR, float2* __restrict__ wsMac)
{
    __shared__ float affs[WPB * B_N * 7];
    const int b   = threadIdx.x & 63;
    const int w   = threadIdx.x >> 6;
    const int blk = blockIdx.x;
    const int base = (blk * BSTEPS + w * MCH) * B_N + b;

    Aff acc = aff_id();
#pragma unroll
    for (int i = 0; i < MCH; ++i) {
        const int idx = base + i * B_N;
        acc = aff_comp(svf_step(g[idx], twoR[idx], audio[idx]), acc);
    }
    aff_store_lds(&affs[(w * B_N + b) * 7], acc);
    __syncthreads();

    if (w == 0) {
        Aff M = acc;  // micro 0 (this wave's own)
#pragma unroll
        for (int j = 1; j < WPB; ++j) {
            Aff A = aff_load_lds(&affs[(j * B_N + b) * 7]);
            M = aff_comp(A, M);
        }
        aff_store_g(&wsMac[(blk * B_N + b) * 3], M);
    }
}

// Pass 2: one block (1024 threads) per batch; thread t owns macro t.
// Wave-inclusive shuffle scan -> wave 0 scans the 16 wave totals ->
// combine -> emit per-macro entry state.
__global__ __launch_bounds__(SC_T, 2) void k_scan(
    const float2* __restrict__ wsMac, float2* __restrict__ sIn)
{
    const int b    = blockIdx.x;   // batch
    const int t    = threadIdx.x;  // macro index
    const int lane = t & 63;
    const int wave = t >> 6;       // 0..15

    Aff m = (t < NBLK) ? aff_load_g(&wsMac[(t * B_N + b) * 3]) : aff_id();

    // wave-inclusive Hillis-Steele scan
    Aff acc = m;
#pragma unroll
    for (int d = 1; d < 64; d <<= 1) {
        Aff o;
        o.m00 = __shfl_up(acc.m00, (unsigned)d, 64);
        o.m01 = __shfl_up(acc.m01, (unsigned)d, 64);
        o.m10 = __shfl_up(acc.m10, (unsigned)d, 64);
        o.m11 = __shfl_up(acc.m11, (unsigned)d, 64);
        o.v0  = __shfl_up(acc.v0,  (unsigned)d, 64);
        o.v1  = __shfl_up(acc.v1,  (unsigned)d, 64);
        if (lane >= d) acc = aff_comp(acc, o);
    }

    __shared__ Aff wt[SC_T / 64];
    if (lane == 63) wt[wave] = acc;
    __syncthreads();

    // wave 0: inclusive scan of the 16 wave totals (lanes 0..15)
    if (wave == 0 && lane < 16) {
        Aff a = wt[lane];
#pragma unroll
        for (int d = 1; d < 16; d <<= 1) {
            Aff o;
            o.m00 = __shfl_up(a.m00, (unsigned)d, 64);
            o.m01 = __shfl_up(a.m01, (unsigned)d, 64);
            o.m10 = __shfl_up(a.m10, (unsigned)d, 64);
            o.m11 = __shfl_up(a.m11, (unsigned)d, 64);
            o.v0  = __shfl_up(a.v0,  (unsigned)d, 64);
            o.v1  = __shfl_up(a.v1,  (unsigned)d, 64);
            if (lane >= d) a = aff_comp(a, o);
        }
        wt[lane] = a;
    }
    __syncthreads();

    if (t < NBLK) {
        // exclusive within wave
        Aff E;
        E.m00 = __shfl_up(acc.m00, 1u, 64);
        E.m01 = __shfl_up(acc.m01, 1u, 64);
        E.m10 = __shfl_up(acc.m10, 1u, 64);
        E.m11 = __shfl_up(acc.m11, 1u, 64);
        E.v0  = __shfl_up(acc.v0,  1u, 64);
        E.v1  = __shfl_up(acc.v1,  1u, 64);
        if (lane == 0) E = aff_id();
        if (wave > 0) E = aff_comp(E, wt[wave - 1]);

        // entry state of macro t: E applied to s0 = (1,1)
        float e0 = E.m00 + E.m01 + E.v0;
        float e1 = E.m10 + E.m11 + E.v1;
        sIn[t * B_N + b] = make_float2(e0, e1);
    }
}

// Pass 3: wave w recomputes its micro transform, block shares micros via
// LDS, wave composes its within-block prefix -> exact entry state, then
// replays only 8 steps. Output transposed through padded LDS tile.
__global__ __launch_bounds__(512, 4) void k_replay(
    const float* __restrict__ audio, const float* __restrict__ g,
    const float* __restrict__ twoR, const float* __restrict__ mix,
    const float2* __restrict__ sIn, float* __restrict__ out)
{
    __shared__ float lds[BSTEPS * 65];  // reused: first WPB*64*7 = Aff staging
    const int b   = threadIdx.x & 63;
    const int w   = threadIdx.x >> 6;
    const int blk = blockIdx.x;
    const int base = (blk * BSTEPS + w * MCH) * B_N + b;

    // load this wave's 8 steps of inputs (all independent -> deep in flight)
    float gv[MCH], Rv[MCH], xv[MCH], m0v[MCH], m1v[MCH], m2v[MCH];
#pragma unroll
    for (int i = 0; i < MCH; ++i) {
        const int idx = base + i * B_N;
        gv[i] = g[idx]; Rv[i] = twoR[idx]; xv[i] = audio[idx];
        m0v[i] = mix[idx * 3]; m1v[i] = mix[idx * 3 + 1]; m2v[i] = mix[idx * 3 + 2];
    }

    // micro transform for this wave
    Aff acc = aff_id();
#pragma unroll
    for (int i = 0; i < MCH; ++i)
        acc = aff_comp(svf_step(gv[i], Rv[i], xv[i]), acc);
    aff_store_lds(&lds[(w * B_N + b) * 7], acc);
    __syncthreads();

    // entry state: within-block exclusive prefix applied to macro entry
    float2 sm = sIn[blk * B_N + b];
    Aff P = aff_id();
    for (int j = 0; j < w; ++j) {
        Aff A = aff_load_lds(&lds[(j * B_N + b) * 7]);
        P = aff_comp(A, P);
    }
    float s0 = fmaf(P.m00, sm.x, fmaf(P.m01, sm.y, P.v0));
    float s1 = fmaf(P.m10, sm.x, fmaf(P.m11, sm.y, P.v1));
    __syncthreads();  // prefix reads done before tile overwrites staging

    // replay 8 steps, write y into transpose tile
#pragma unroll
    for (int i = 0; i < MCH; ++i) {
        float gg = gv[i], R = Rv[i], x = xv[i];
        float T  = 1.0f / fmaf(gg, gg + R, 1.0f);
        float gT = gg * T;
        float b0 = gT * x;
        float b1 = gg * b0;
        float Y0 = fmaf(T, s0, fmaf(-gT, s1, b0));
        float Y1 = fmaf(gT, s0, fmaf(fmaf(R, gT, T), s1, b1));
        s0 = fmaf(2.0f, Y0, -s0);
        s1 = fmaf(2.0f, Y1, -s1);

        float yh = x - fmaf(R, Y0, Y1);
        float y  = fmaf(R * m0v[i], Y0, fmaf(m1v[i], Y1, m2v[i] * yh));

        lds[(w * MCH + i) * 65 + b] = y;
    }
    __syncthreads();

    // out[r][blk*64 + col]: 64-lane contiguous 256 B stores; LDS reads
    // stride-65 -> 2-way max (free)
    const int col = threadIdx.x & 63;
    const int r0  = threadIdx.x >> 6;
    const int colbase = blk * BSTEPS;
#pragma unroll
    for (int r = r0; r < B_N; r += WPB) {
        out[r * S_LEN + colbase + col] = lds[col * 65 + r];
    }
}

extern "C" void kernel_launch(void* const* d_in, const int* in_sizes, int n_in,
                              void* d_out, int out_size, void* d_ws, size_t ws_size,
                              hipStream_t stream)
{
    const float* audio = (const float*)d_in[0];
    const float* g     = (const float*)d_in[1];
    const float* twoR  = (const float*)d_in[2];
    const float* mix   = (const float*)d_in[3];
    float* out = (float*)d_out;

    float2* wsMac = (float2*)d_ws;               // NBLK*64*3 float2 (~1.5 MB)
    float2* sIn   = wsMac + NBLK * B_N * 3;      // NBLK*64 float2 (~0.5 MB)

    k_macro <<<dim3(NBLK), dim3(512), 0, stream>>>(audio, g, twoR, wsMac);
    k_scan  <<<dim3(B_N), dim3(SC_T), 0, stream>>>(wsMac, sIn);
    k_replay<<<dim3(NBLK), dim3(512), 0, stream>>>(audio, g, twoR, mix, sIn, out);
}